// Round 17
// baseline (259.657 us; speedup 1.0000x reference)
//
#include <hip/hip_runtime.h>
#include <stdint.h>

// B=4, S=2048, D=1024, H=16, Hd=64, M=8192.
// Pipeline: prep (cast x + W^T casts); merged QKV GEMM (128^2 row-major,
// BK=128, XCD-chunked; Q pre-scaled; V written TRANSPOSED from epilogue);
// flash attn (S^T = K@Q^T key-permutation trick); O-proj GEMM (BK=128).
// Ledger: R2 XCD decode (attn FETCH 139->25MB). R3 setprio hurts lockstep.
// R10 V^T fused (-1 kernel). R11 frag-major LDS breaks global coalescing
// with global_load_lds -> row-major+conflict is GEMM local optimum.
// R13/R14 megakernel abandoned (grid.sync unreliable under graph capture).
// R15/R16 BK 32->64->128: drain amortization (m233) -> 260.9 -> 257.6 best.
// R17: attn is top dispatch (77.8us, 6.29M conflict cyc). Stride 72 ushort
// = 36 dwords = 4 mod 32 -> frag reads hit only 8 banks (8-way). Any 16B
// stride caps at 8 banks; stride 76 (38 dwords = 6 mod 32) spreads l16 over
// 16 banks (~2-way residual, free per m136). Requires 8B ops: kf b128 ->
// 2x b64, staging b128 stores -> 2x b64 (writes also 8-way -> 4-way).

typedef float f32x4 __attribute__((ext_vector_type(4)));
typedef __bf16 bf16x4 __attribute__((ext_vector_type(4)));
typedef __bf16 bf16x8 __attribute__((ext_vector_type(8)));
typedef uint32_t u32x4 __attribute__((ext_vector_type(4)));
typedef uint32_t u32x2 __attribute__((ext_vector_type(2)));

#define MFMA16(a, b, c) __builtin_amdgcn_mfma_f32_16x16x32_bf16((a), (b), (c), 0, 0, 0)

// Q pre-scale: log2(e)/8 so attn does p = exp2(Q'.K) = e^{QK/8} (unnormalized)
#define QSCALE 0.1803368801111204f

__device__ __forceinline__ unsigned short f2bf(float f) {
  union { float f; uint32_t u; } c; c.f = f;
  uint32_t u = c.u;
  return (unsigned short)((u + 0x7fffu + ((u >> 16) & 1u)) >> 16);  // RNE
}

// ---------------------------------------------------------------- prep
// blocks [0,8192): cast x (fp32 -> bf16, float4/ushort4 vectorized).
// blocks [8192,12288): W^T casts — 4 weights [k][n] fp32 -> Wt [n][k] bf16,
// 32x32 LDS tile per block (1024 blocks per weight).
__global__ __launch_bounds__(256) void prep_kernel(const float* __restrict__ x,
                                                   unsigned short* __restrict__ xb,
                                                   const float* __restrict__ W0,
                                                   const float* __restrict__ W1,
                                                   const float* __restrict__ W2,
                                                   const float* __restrict__ W3,
                                                   unsigned short* __restrict__ Wt) {
  __shared__ float tile[32][33];
  const int id = blockIdx.x;
  const int tid = threadIdx.x;
  if (id < 8192) {
    int i = id * 256 + tid;  // exactly 2097152 float4s
    float4 v = ((const float4*)x)[i];
    ushort4 o;
    o.x = f2bf(v.x); o.y = f2bf(v.y); o.z = f2bf(v.z); o.w = f2bf(v.w);
    ((ushort4*)xb)[i] = o;
  } else {
    const int t = id - 8192;
    const int z = t >> 10, r = t & 1023;
    const int k0 = (r >> 5) * 32, n0 = (r & 31) * 32;
    const float* W = (z == 0) ? W0 : (z == 1) ? W1 : (z == 2) ? W2 : W3;
    unsigned short* dst = Wt + (size_t)z * 1048576;
    const int tx = tid & 31, ty = tid >> 5;  // 32 x 8
#pragma unroll
    for (int i = 0; i < 32; i += 8)
      tile[ty + i][tx] = W[(size_t)(k0 + ty + i) * 1024 + n0 + tx];
    __syncthreads();
#pragma unroll
    for (int i = 0; i < 32; i += 8)
      dst[(size_t)(n0 + ty + i) * 1024 + k0 + tx] = f2bf(tile[tx][ty + i]);
  }
}

// ---------------------------------------------------------------- GEMM 128^2, BK=128
// MODE 0: O-proj. out fp32 [8192][1024], bias b0. grid 512 flat.
// MODE 1: merged QKV. Bt = [3072][1024], out = QKV bf16 base (Q,K scatter to
//         [b,h,s,hd]; Q scaled by QSCALE); mb==2 (V) written TRANSPOSED to
//         vtg[bh][hd][s] as 8B ushort4 (4 consecutive s). grid 1536 flat.
// XCD-chunked decode: XCD x owns by in [8x, 8x+8); bx-major, by-inner.
// LDS = eight 128x32 row-major subtiles (A k0..k3 | B k0..k3, 64KB): one
// __syncthreads pair per 128 K (drain amortized over 64 MFMAs — m233/R15/R16).
template <int MODE>
__global__ __launch_bounds__(256) void gemm128(const unsigned short* __restrict__ A,
                                               const unsigned short* __restrict__ Bt,
                                               const float* __restrict__ b0,
                                               const float* __restrict__ b1,
                                               const float* __restrict__ b2,
                                               void* __restrict__ out,
                                               unsigned short* __restrict__ vtg) {
  constexpr int Kd = 1024;
  __shared__ unsigned short sm[32768];  // 64 KB: A[4 subtiles 4096 each] | B[4 subtiles], ushorts
  auto lds3 = (__attribute__((address_space(3))) char*)sm;

  const int tid = threadIdx.x;
  const int wave = tid >> 6, lane = tid & 63, quad = lane >> 4, l16 = lane & 15;
  const int wm = wave >> 1, wn = wave & 1;

  const int id = blockIdx.x;
  const int nid = id >> 3;
  const int by = (id & 7) * 8 + (nid & 7);
  const int bx = nid >> 3;
  const int bm = by * 128, bn = bx * 128;

  f32x4 acc[4][4] = {};

  for (int k0 = 0; k0 < Kd; k0 += 128) {
#pragma unroll
    for (int j = 0; j < 2; ++j) {
      int i = (wave * 2 + j) * 64 + lane;  // 16B-chunk 0..511 of a 128x32 subtile
      const int lo = (wave * 2 + j) * 1024;  // wave-uniform LDS byte base
      const unsigned short* ga = A + (size_t)(bm + (i >> 2)) * Kd + k0 + (i & 3) * 8;
      const unsigned short* gb = Bt + (size_t)(bn + (i >> 2)) * Kd + k0 + (i & 3) * 8;
#pragma unroll
      for (int s = 0; s < 4; ++s) {
        __builtin_amdgcn_global_load_lds(
            (const __attribute__((address_space(1))) void*)(ga + s * 32),
            (__attribute__((address_space(3))) void*)(lds3 + s * 8192 + lo), 16, 0, 0);
        __builtin_amdgcn_global_load_lds(
            (const __attribute__((address_space(1))) void*)(gb + s * 32),
            (__attribute__((address_space(3))) void*)(lds3 + 32768 + s * 8192 + lo), 16, 0, 0);
      }
    }
    __syncthreads();

    bf16x8 af[4], bfv[4];
#pragma unroll
    for (int s = 0; s < 4; ++s) {
      // subtile s: A at ushort offset s*4096, B at 16384 + s*4096
#pragma unroll
      for (int i = 0; i < 4; ++i)
        af[i] = *(const bf16x8*)(sm + s * 4096 + (wm * 64 + i * 16 + l16) * 32 + quad * 8);
#pragma unroll
      for (int n = 0; n < 4; ++n)
        bfv[n] = *(const bf16x8*)(sm + 16384 + s * 4096 + (wn * 64 + n * 16 + l16) * 32 + quad * 8);
#pragma unroll
      for (int i = 0; i < 4; ++i)
#pragma unroll
        for (int n = 0; n < 4; ++n)
          acc[i][n] = MFMA16(af[i], bfv[n], acc[i][n]);
    }
    __syncthreads();
  }

  // epilogue: C/D layout col=lane&15, row=quad*4+reg
  const int mb = bn >> 10;  // matrix id for MODE 1 (block never straddles: 1024%128==0)
  const float* bias = (MODE == 0) ? b0 : (mb == 0 ? b0 : (mb == 1 ? b1 : b2));
  const float scale = (MODE == 1 && mb == 0) ? QSCALE : 1.0f;
  unsigned short* oq = (MODE == 1) ? ((unsigned short*)out + (size_t)mb * 8388608u) : nullptr;

#pragma unroll
  for (int i = 0; i < 4; ++i) {
    const int row0 = bm + wm * 64 + i * 16 + quad * 4;
#pragma unroll
    for (int n = 0; n < 4; ++n) {
      const int col = bn + wn * 64 + n * 16 + l16;
      const int cl = col & 1023;
      const float bv = bias[cl];
      if (MODE == 1 && mb == 2) {
        // V^T: vtg[(b*16+h)][hd][s], 4 consecutive s per thread -> 8B store
        const int h = cl >> 6, hd = cl & 63;
        const int b = row0 >> 11, s0v = row0 & 2047;
        ushort4 pk;
        pk.x = f2bf(acc[i][n][0] + bv);
        pk.y = f2bf(acc[i][n][1] + bv);
        pk.z = f2bf(acc[i][n][2] + bv);
        pk.w = f2bf(acc[i][n][3] + bv);
        *(ushort4*)(vtg + (size_t)(b * 16 + h) * 131072 + (size_t)hd * 2048 + s0v) = pk;
      } else {
#pragma unroll
        for (int r = 0; r < 4; ++r) {
          float v = (acc[i][n][r] + bv) * scale;
          if (MODE == 0) {
            ((float*)out)[(size_t)(row0 + r) * 1024 + col] = v;
          } else {
            int rr = row0 + r;
            int b = rr >> 11, s = rr & 2047;
            int h = cl >> 6, hd = cl & 63;
            oq[((size_t)(b * 16 + h) * 2048 + s) * 64 + hd] = f2bf(v);
          }
        }
      }
    }
  }
}

// ---------------------------------------------------------------- flash attention
// Q pre-scaled. 512 flat blocks; block = (b,h) x 256 q-rows; wave = 64 q-rows
// (4 subtiles). XCD-grouped decode: bh = (id&7)*8 + ((id>>3)>>3) so all 8
// q-blocks of a head (and 8 whole heads) land on one XCD -> K/Vt L2-resident
// (proven R2/R3: FETCH 139 -> 25 MB). No setprio: lockstep loop (m190/R3).
// S^T = K(A) @ Q^T(B): C-layout puts col=l16=qrow, so each lane's 16 exp2'd
// scores (keys quad*4+r per subtile) form PV A-frags directly under the key
// permutation sigma(q*8+j) = st*32 + (j>>2)*16 + q*4 + (j&3); V B-frags use
// the same sigma (two contiguous b64 chunks from the Vt tile). No P in LDS.
// R17: row stride 76 ushorts (38 dwords = 6 mod 32): l16*6 mod 32 covers 16
// distinct banks (~2-way residual, free) vs stride 72's 8 banks (8-way,
// 6.29M conflict cyc). 8B-aligned rows -> all LDS ops are b64.
#define KVS 76      // row stride in ushorts (152 B, 8B-aligned)
#define VOFF 4864   // 64*76: V base within a buffer
__global__ __launch_bounds__(256, 2) void attn_kernel(const unsigned short* __restrict__ Q,
                                                      const unsigned short* __restrict__ K,
                                                      const unsigned short* __restrict__ Vt,
                                                      unsigned short* __restrict__ ctx) {
  const int tid = threadIdx.x;
  const int wave = tid >> 6, lane = tid & 63, quad = lane >> 4, l16 = lane & 15;

  const int id = blockIdx.x;
  const int bh = (id & 7) * 8 + ((id >> 3) >> 3);  // 8 heads per XCD
  const int qx = (id >> 3) & 7;

  // double buffer: [buf][Ks 64*KVS | Vts 64*KVS]
  __shared__ unsigned short sm[2][2 * 64 * KVS];

  const size_t hb = (size_t)bh * 131072;
  const int q0 = qx * 256 + wave * 64;

  // Q B-frags: B[k=hd][n=qrow]: lane l16 = qrow, k = quad*8+j (+32*st)
  bf16x8 qf[4][2];
#pragma unroll
  for (int qt = 0; qt < 4; ++qt)
#pragma unroll
    for (int st = 0; st < 2; ++st)
      qf[qt][st] = *(const bf16x8*)(Q + hb + (size_t)(q0 + qt * 16 + l16) * 64 + st * 32 + quad * 8);

  f32x4 o[4][4] = {};
  float lacc[4] = {0.f, 0.f, 0.f, 0.f};

  // staging: 4 x 16B chunks/thread (2 K rows-of-keys + 2 Vt rows-of-hd);
  // LDS stores as 2x b64 (rows are 8B-aligned at stride 152B)
  const int c0 = tid, c1 = tid + 256;
  const unsigned short* gK0 = K + hb + (size_t)(c0 >> 3) * 64 + (c0 & 7) * 8;
  const unsigned short* gK1 = K + hb + (size_t)(c1 >> 3) * 64 + (c1 & 7) * 8;
  const unsigned short* gV0 = Vt + hb + (size_t)(c0 >> 3) * 2048 + (c0 & 7) * 8;
  const unsigned short* gV1 = Vt + hb + (size_t)(c1 >> 3) * 2048 + (c1 & 7) * 8;
  const int sKo = (c0 >> 3) * KVS + (c0 & 7) * 8;
  const int sKo1 = (c1 >> 3) * KVS + (c1 & 7) * 8;

#define ST16(dst, v)                                   \
  do {                                                 \
    *(u32x2*)(dst) = (u32x2){(v)[0], (v)[1]};          \
    *(u32x2*)((dst) + 4) = (u32x2){(v)[2], (v)[3]};    \
  } while (0)

  u32x4 pk0 = *(const u32x4*)gK0, pk1 = *(const u32x4*)gK1;
  u32x4 pv0 = *(const u32x4*)gV0, pv1 = *(const u32x4*)gV1;
  {
    unsigned short* s0b = sm[0];
    ST16(s0b + sKo, pk0); ST16(s0b + sKo1, pk1);
    ST16(s0b + VOFF + sKo, pv0); ST16(s0b + VOFF + sKo1, pv1);
  }
  __syncthreads();

  for (int kb = 0; kb < 2048; kb += 64) {
    const int cur = (kb >> 6) & 1;
    const bool more = (kb + 64) < 2048;
    if (more) {
      pk0 = *(const u32x4*)(gK0 + (size_t)(kb + 64) * 64);
      pk1 = *(const u32x4*)(gK1 + (size_t)(kb + 64) * 64);
      pv0 = *(const u32x4*)(gV0 + kb + 64);
      pv1 = *(const u32x4*)(gV1 + kb + 64);
    }
    const unsigned short* Ks = sm[cur];
    const unsigned short* Vts = sm[cur] + VOFF;

    // K A-frags: A[m=key][k=hd]: lane l16 = key (per subtile ks), contiguous
    // hd; two b64 halves (rows 8B-aligned)
    bf16x8 kf[4][2];
#pragma unroll
    for (int ks = 0; ks < 4; ++ks)
#pragma unroll
      for (int st = 0; st < 2; ++st) {
        const unsigned short* kp = Ks + (ks * 16 + l16) * KVS + st * 32 + quad * 8;
        bf16x4 klo = *(const bf16x4*)kp;
        bf16x4 khi = *(const bf16x4*)(kp + 4);
        kf[ks][st] = __builtin_shufflevector(klo, khi, 0, 1, 2, 3, 4, 5, 6, 7);
      }

    // V B-frags under sigma: two b64 chunks (keys st*32+quad*4+{0..3}, +16)
    bf16x8 vf[4][2];
#pragma unroll
    for (int os = 0; os < 4; ++os)
#pragma unroll
      for (int st = 0; st < 2; ++st) {
        const unsigned short* rb = Vts + (os * 16 + l16) * KVS + st * 32 + quad * 4;
        bf16x4 a = *(const bf16x4*)rb;
        bf16x4 b2 = *(const bf16x4*)(rb + 16);
        vf[os][st] = __builtin_shufflevector(a, b2, 0, 1, 2, 3, 4, 5, 6, 7);
      }

#pragma unroll
    for (int qt = 0; qt < 4; ++qt) {
      // S^T tiles: rows = keys (quad*4+r), cols = qrows (l16)
      f32x4 sc[4];
#pragma unroll
      for (int ks = 0; ks < 4; ++ks) {
        f32x4 a = {0.f, 0.f, 0.f, 0.f};
        a = MFMA16(kf[ks][0], qf[qt][0], a);
        a = MFMA16(kf[ks][1], qf[qt][1], a);
        sc[ks] = a;
      }
      // exp2 -> P A-frags in-register; per-lane l partials (all for qrow l16)
      bf16x8 pf[2];
      float ls = 0.f;
#pragma unroll
      for (int ks = 0; ks < 4; ++ks)
#pragma unroll
        for (int r = 0; r < 4; ++r) {
          float p = __builtin_amdgcn_exp2f(sc[ks][r]);
          ls += p;
          pf[ks >> 1][(ks & 1) * 4 + r] = (__bf16)p;
        }
      lacc[qt] += ls;
#pragma unroll
      for (int st = 0; st < 2; ++st)
#pragma unroll
        for (int os = 0; os < 4; ++os)
          o[qt][os] = MFMA16(pf[st], vf[os][st], o[qt][os]);
    }

    if (more) {
      unsigned short* sn = sm[cur ^ 1];
      ST16(sn + sKo, pk0); ST16(sn + sKo1, pk1);
      ST16(sn + VOFF + sKo, pv0); ST16(sn + VOFF + sKo1, pv1);
    }
    __syncthreads();
  }
#undef ST16

  // finalize: reduce l across quads (lane's l16 = qrow), redistribute to
  // C-layout rows (quad*4+r), normalize, store.
  const int b = bh >> 4, h = bh & 15;
#pragma unroll
  for (int qt = 0; qt < 4; ++qt) {
    float l = lacc[qt];
    l += __shfl_xor(l, 16, 64);
    l += __shfl_xor(l, 32, 64);
#pragma unroll
    for (int r = 0; r < 4; ++r) {
      float lr = __shfl(l, quad * 4 + r, 16);
      float inv = 1.0f / lr;
      int s = q0 + qt * 16 + quad * 4 + r;
#pragma unroll
      for (int os = 0; os < 4; ++os)
        ctx[((size_t)(b * 2048 + s)) * 1024 + h * 64 + os * 16 + l16] = f2bf(o[qt][os][r] * inv);
    }
  }
}

// ---------------------------------------------------------------- launch
extern "C" void kernel_launch(void* const* d_in, const int* in_sizes, int n_in,
                              void* d_out, int out_size, void* d_ws, size_t ws_size,
                              hipStream_t stream) {
  const float* x  = (const float*)d_in[0];
  const float* Wq = (const float*)d_in[1];
  const float* bq = (const float*)d_in[2];
  const float* Wk = (const float*)d_in[3];
  const float* bk = (const float*)d_in[4];
  const float* Wv = (const float*)d_in[5];
  const float* bv = (const float*)d_in[6];
  const float* Wo = (const float*)d_in[7];
  const float* bo = (const float*)d_in[8];

  unsigned short* ws = (unsigned short*)d_ws;
  unsigned short* xb    = ws;                    // 8388608  A input; attn out after QKV
  unsigned short* Wtall = ws + 8388608;          // 4*1048576 (Wq^T|Wk^T|Wv^T|Wo^T)
  unsigned short* Wot   = Wtall + 3145728;
  unsigned short* Qb    = Wtall + 4194304;       // 8388608  [bh][s][hd], pre-scaled
  unsigned short* Kb    = Qb + 8388608;          // 8388608  [bh][s][hd]
  unsigned short* VtG   = Kb + 8388608;          // 8388608  [bh][hd][s] (written by QKV epilogue)
  unsigned short* Cb    = xb;                    // alias: xb dead after QKV GEMM

  prep_kernel<<<dim3(12288), 256, 0, stream>>>(x, xb, Wq, Wk, Wv, Wo, Wtall);
  gemm128<1><<<dim3(1536), 256, 0, stream>>>(xb, Wtall, bq, bk, bv, Qb, VtG);
  attn_kernel<<<dim3(512), 256, 0, stream>>>(Qb, Kb, VtG, Cb);
  gemm128<0><<<dim3(512), 256, 0, stream>>>(Cb, Wot, bo, nullptr, nullptr, d_out, nullptr);
}